// Round 9
// baseline (1386.490 us; speedup 1.0000x reference)
//
#include <hip/hip_runtime.h>
#include <math.h>

#define Hn   256
#define En   128
#define Vn   256
#define TPn  32
#define BTn  2048
#define NSV  8
#define NWG  (BTn / NSV)
#define NT   1024

#define KATTR __attribute__((amdgpu_flat_work_group_size(1024, 1024), amdgpu_waves_per_eu(4, 4)))

typedef __attribute__((ext_vector_type(8))) short bf16x8;
typedef __attribute__((ext_vector_type(4))) float f32x4;

__device__ __forceinline__ float sigf(float x) {
    return __builtin_amdgcn_rcpf(1.0f + __expf(-x));
}
__device__ __forceinline__ float tanh_fast(float x) {
    float e = __expf(2.0f * x);
    return 1.0f - 2.0f * __builtin_amdgcn_rcpf(e + 1.0f);
}
__device__ __forceinline__ unsigned bf16rne(float x) {
    unsigned b = __float_as_uint(x);
    return (b + 0x7FFFu + ((b >> 16) & 1u)) >> 16;
}
__device__ __forceinline__ unsigned pk2(float a, float b) {
    return bf16rne(a) | (bf16rne(b) << 16);
}
__device__ __forceinline__ float bfu(unsigned short x) {
    return __uint_as_float(((unsigned)x) << 16);
}
__device__ __forceinline__ unsigned long long amax_key(float sc, int v) {
    unsigned fb = __float_as_uint(sc);
    fb = (fb & 0x80000000u) ? ~fb : (fb | 0x80000000u);
    return ((unsigned long long)fb << 32) | (unsigned)(Vn - 1 - v);
}
__device__ __forceinline__ float dot4(float4 a, float4 b, float acc) {
    return fmaf(a.x, b.x, fmaf(a.y, b.y, fmaf(a.z, b.z, fmaf(a.w, b.w, acc))));
}

// raw barrier with LDS-publish only: NO vmcnt drain (keeps DMA prefetch in flight)
__device__ __forceinline__ void barL() {
    asm volatile("s_waitcnt lgkmcnt(0)" ::: "memory");
    __builtin_amdgcn_s_barrier();
    __builtin_amdgcn_sched_barrier(0);
}
#define VMW(n) asm volatile("s_waitcnt vmcnt(" #n ")" ::: "memory")

// async global->LDS, 16B per lane. LDS dest = wave-uniform base + lane*16 (HW),
// global src is per-lane (must include lane*16).
#define GLL(gp, lp) __builtin_amdgcn_global_load_lds( \
    (const __attribute__((address_space(1))) unsigned int*)(const void*)(gp), \
    (__attribute__((address_space(3))) unsigned int*)(void*)(lp), 16, 0, 0)

// ---------------- precompute ----------------

__global__ void make_ptab(float4* __restrict__ Pp, const float* __restrict__ emb,
                          const float* __restrict__ Wih, const float* __restrict__ bih,
                          const float* __restrict__ bhh) {
    int v = blockIdx.x, u = threadIdx.x;
    __shared__ __align__(16) float es[En];
    if (u < En) es[u] = emb[v * En + u];
    __syncthreads();
    float a[4];
#pragma unroll
    for (int g = 0; g < 4; ++g) {
        int r = g * Hn + u;
        float acc = bih[r] + bhh[r];
        const float4* w4 = (const float4*)(Wih + r * En);
        const float4* e4 = (const float4*)es;
        for (int k = 0; k < En / 4; ++k) acc = dot4(w4[k], e4[k], acc);
        a[g] = acc;
    }
    Pp[v * Hn + u] = make_float4(a[0], a[1], a[2], a[3]);
}

// q-major A-fragment pack: A[((q*ntile + t)*64 + l)] = 8 bf16 of
// Wcat[16t + (l&15)][32q + 8*(l>>4) .. +7], Wcat = Whh rows 0..1023 (+ fcW rows for dec).
// Chunk (q, half) is then a contiguous block -> linear global_load_lds staging.
__global__ void pack_awq(uint4* __restrict__ A, const float* __restrict__ Whh,
                         const float* __restrict__ fcW, int ntile) {
    int idx = blockIdx.x * 256 + threadIdx.x;
    if (idx >= ntile * 8 * 64) return;
    int l = idx & 63, tq = idx >> 6;
    int t = tq % ntile, q = tq / ntile;
    int r = 16 * t + (l & 15);
    int kb = 32 * q + 8 * (l >> 4);
    const float* s = (r < 1024) ? (Whh + r * Hn + kb) : (fcW + (r - 1024) * Hn + kb);
    A[idx] = make_uint4(pk2(s[0], s[1]), pk2(s[2], s[3]), pk2(s[4], s[5]), pk2(s[6], s[7]));
}

// ---------------- encoder ----------------
// LDS map: [0,98304) 3 slots x 32768 | [98304,106496) hBf | [106496,143360) gact f32[1024][9]
//          [143360,+32) lsh
// 16 phases/iter (q 0..7 x half), 3-slot ring, chunks via global_load_lds, counted vmcnt.
__global__ KATTR void enc_kernel(
    const char* __restrict__ AWq, const float4* __restrict__ Ptu,
    const int* __restrict__ phon, const int* __restrict__ lens,
    float* __restrict__ h0dec) {
    const int tid = threadIdx.x, wg = blockIdx.x;
    const int wv = tid >> 6, l = tid & 63;
    const int c16 = l & 15, rg = l >> 4;
    const int u = tid >> 2, ch = tid & 3;
    const int sA = 2 * ch, sB = sA + 1;
    __shared__ __align__(16) char LB[143392];
    uint4* hBf  = (uint4*)(LB + 98304);
    float* gact = (float*)(LB + 106496);
    int*   lsh  = (int*)(LB + 143360);

    if (tid < 512) hBf[tid] = make_uint4(0u, 0u, 0u, 0u);
    if (tid < NSV) lsh[tid] = lens[wg * NSV + tid];

    const int baseA = (wg * NSV + sA) * TPn, baseB = (wg * NSV + sB) * TPn;
    const char* gq = AWq + wv * 2048 + l * 16;   // per-lane global base
    char* lsW = LB + wv * 2048;                  // wave-uniform LDS slice base

    // prologue: tok0, tok1, chunks 0,1, Ptu(t=0)
    int tokA1, tokB1;
    int tA0 = phon[baseA + 0], tB0 = phon[baseB + 0];
    tokA1 = phon[baseA + 1]; tokB1 = phon[baseB + 1];
    GLL(gq + 0,            lsW + 0);
    GLL(gq + 1024,         lsW + 1024);
    GLL(gq + 32768,        lsW + 32768);
    GLL(gq + 32768 + 1024, lsW + 32768 + 1024);
    float4 pA = Ptu[tA0 * Hn + u];
    float4 pB = Ptu[tB0 * Hn + u];
    float cA = 0.f, cB = 0.f;
    VMW(2);          // chunk0 landed (only chunk1's 2 newer among GLLs)
    barL();

    int mx = 0;
#pragma unroll
    for (int i2 = 0; i2 < NSV; ++i2) mx = max(mx, lsh[i2]);
    const int lenA = lsh[sA], lenB = lsh[sB];
    const int hmine = (wv >= 8) ? 1 : 0;
    const int tlb = (4 * wv - 32 * hmine) * 1024;   // wave's first tile byte-offset in chunk

    for (int t = 0; t < mx; ++t) {
        f32x4 acc[4];
#pragma unroll
        for (int ii = 0; ii < 4; ++ii) acc[ii] = (f32x4){0.f, 0.f, 0.f, 0.f};
#pragma unroll
        for (int p = 0; p < 16; ++p) {
            if ((p & 1) == hmine) {
                const int q = p >> 1, s = p % 3;
                bf16x8 bfq = *(const bf16x8*)&hBf[q * 64 + l];
                const char* sp = LB + s * 32768 + tlb + l * 16;
#pragma unroll
                for (int ii = 0; ii < 4; ++ii)
                    acc[ii] = __builtin_amdgcn_mfma_f32_16x16x32_bf16(
                        *(const bf16x8*)(sp + ii * 1024), bfq, acc[ii], 0, 0, 0);
            }
            if (p < 15) {
                barL();                              // close consumption of p
                if (p < 14) {
                    const int pn = p + 2, sn = pn % 3;
                    GLL(gq + pn * 32768,        lsW + sn * 32768);
                    GLL(gq + pn * 32768 + 1024, lsW + sn * 32768 + 1024);
                    VMW(2);                          // chunk p+1 landed
                } else {
                    VMW(0);                          // chunk 15 landed
                }
                barL();                              // publish p+1
            }
        }
        if (c16 < 8) {   // C: col=lane&15 (seq), row=(lane>>4)*4+reg [m89-verified]
#pragma unroll
            for (int ii = 0; ii < 4; ++ii) {
                const int Rb = (4 * wv + ii) * 16 + rg * 4;
#pragma unroll
                for (int r = 0; r < 4; ++r) gact[(Rb + r) * 9 + c16] = acc[ii][r];
            }
        }
        barL();   // closes slot reads (phase 15) + publishes gact

        float g0A = gact[u * 9 + sA],         g0B = gact[u * 9 + sB];
        float g1A = gact[(256 + u) * 9 + sA], g1B = gact[(256 + u) * 9 + sB];
        float g2A = gact[(512 + u) * 9 + sA], g2B = gact[(512 + u) * 9 + sB];
        float g3A = gact[(768 + u) * 9 + sA], g3B = gact[(768 + u) * 9 + sB];
        float hvA, hvB;
        {
            float gi = sigf(g0A + pA.x), gf = sigf(g1A + pA.y);
            float gg = tanh_fast(g2A + pA.z), go = sigf(g3A + pA.w);
            cA = fmaf(gf, cA, gi * gg); hvA = go * tanh_fast(cA);
        }
        {
            float gi = sigf(g0B + pB.x), gf = sigf(g1B + pB.y);
            float gg = tanh_fast(g2B + pB.z), go = sigf(g3B + pB.w);
            cB = fmaf(gf, cB, gi * gg); hvB = go * tanh_fast(cB);
        }
        // ---- tail: Ptu(t+1), tok(t+2), next-iter chunks 0,1 ----
        const bool more = (t + 1 < mx);
        if (more) {
            pA = Ptu[tokA1 * Hn + u];               // tok for t+1 (loaded last tail)
            pB = Ptu[tokB1 * Hn + u];
            int t2 = (t + 2 <= TPn - 1) ? (t + 2) : (TPn - 1);
            tokA1 = phon[baseA + t2];
            tokB1 = phon[baseB + t2];
            GLL(gq + 0,            lsW + 0);        // next iter chunk 0 -> slot 0
            GLL(gq + 1024,         lsW + 1024);
            GLL(gq + 32768,        lsW + 32768);    // chunk 1 -> slot 1
            GLL(gq + 32768 + 1024, lsW + 32768 + 1024);
        }
        if (t == lenA - 1) h0dec[(wg * NSV + sA) * Hn + u] = hvA;
        if (t == lenB - 1) h0dec[(wg * NSV + sB) * Hn + u] = hvB;
        {   // new h into B-fragment layout (k=u -> q=u>>5, g=(u>>3)&3, j=u&7)
            unsigned short* hb16 = (unsigned short*)hBf;
            const int qh = u >> 5, gh = (u >> 3) & 3, jh = u & 7;
            hb16[(qh * 64 + gh * 16 + sA) * 8 + jh] = (unsigned short)bf16rne(hvA);
            hb16[(qh * 64 + gh * 16 + sB) * 8 + jh] = (unsigned short)bf16rne(hvB);
        }
        if (more) VMW(2);                            // next chunk 0 landed (keep chunk 1 flying)
        barL();                                      // publishes h + next chunk 0
    }
}

// ---------------- decoder ----------------
// M=1280 (1024 gates + 256 fc). LDS map:
// [0,122880) 3 slots x 40960 | [122880,131072) hBf | [131072,149504) gactG u16[1024][9]
// [149504,158720) gactF f32[256][9] | [158720,158848) gmax[2][8]
// Gates round-trip as bf16 (precision: same class as bf16-h); scores stay f32.
__global__ KATTR void dec_kernel(
    const char* __restrict__ AWq, const float4* __restrict__ Ptu,
    const float* __restrict__ fcb, const float* __restrict__ h0dec,
    const int* __restrict__ sosp, float* __restrict__ out) {
    const int tid = threadIdx.x, wg = blockIdx.x;
    const int wv = tid >> 6, l = tid & 63;
    const int c16 = l & 15, rg = l >> 4;
    const int u = tid >> 2, ch = tid & 3;
    const int sA = 2 * ch, sB = sA + 1;
    const int ln = tid & 63;
    __shared__ __align__(16) char LB[158848];
    uint4* hBf = (uint4*)(LB + 122880);
    unsigned short* gactG = (unsigned short*)(LB + 131072);
    float* gactF = (float*)(LB + 149504);
    unsigned long long* gmax = (unsigned long long*)(LB + 158720);

    if (tid < 512) {   // stage h0 into B-fragment layout
        int qq = tid >> 6, ll = tid & 63, c = ll & 15, g = ll >> 4;
        uint4 v = make_uint4(0u, 0u, 0u, 0u);
        if (c < 8) {
            const float* hp = h0dec + (wg * NSV + c) * Hn + 32 * qq + 8 * g;
            float4 v0 = *(const float4*)hp;
            float4 v1 = *(const float4*)(hp + 4);
            v = make_uint4(pk2(v0.x, v0.y), pk2(v0.z, v0.w), pk2(v1.x, v1.y), pk2(v1.z, v1.w));
        }
        hBf[tid] = v;
    }
    if (tid < 16) gmax[tid] = 0ull;
    const int sos0 = sosp[0];
    const float fb = fcb[u];

    const char* gq = AWq + wv * 4096 + l * 16;
    char* lsW = LB + wv * 4096;
    const bool ldr = (wv < 10);    // waves 0..9 load 4 KB per 40 KB chunk
#define DGLL(pp, ss) do { \
        GLL(gq + (pp) * 40960 + 0,    lsW + (ss) * 40960 + 0);    \
        GLL(gq + (pp) * 40960 + 1024, lsW + (ss) * 40960 + 1024); \
        GLL(gq + (pp) * 40960 + 2048, lsW + (ss) * 40960 + 2048); \
        GLL(gq + (pp) * 40960 + 3072, lsW + (ss) * 40960 + 3072); } while (0)

    float4 pA = Ptu[sos0 * Hn + u];
    float4 pB = pA;
    if (ldr) { DGLL(0, 0); DGLL(1, 1); VMW(4); }
    float cA = 0.f, cB = 0.f;
    barL();

    const int hmine = (wv >= 8) ? 1 : 0;
    const int tlb = (5 * wv - 40 * hmine) * 1024;

    for (int i = 0; i <= TPn; ++i) {
        f32x4 acc[5];
#pragma unroll
        for (int ii = 0; ii < 5; ++ii) acc[ii] = (f32x4){0.f, 0.f, 0.f, 0.f};
#pragma unroll
        for (int p = 0; p < 16; ++p) {
            if ((p & 1) == hmine) {
                const int q = p >> 1, s = p % 3;
                bf16x8 bfq = *(const bf16x8*)&hBf[q * 64 + l];
                const char* sp = LB + s * 40960 + tlb + l * 16;
#pragma unroll
                for (int ii = 0; ii < 5; ++ii)
                    acc[ii] = __builtin_amdgcn_mfma_f32_16x16x32_bf16(
                        *(const bf16x8*)(sp + ii * 1024), bfq, acc[ii], 0, 0, 0);
            }
            if (p < 15) {
                barL();
                if (ldr) {
                    if (p < 14) { DGLL(p + 2, (p + 2) % 3); VMW(4); }
                    else VMW(0);
                }
                barL();
            }
        }
        // C-write: gate rows bf16, fc rows f32
        if (c16 < 8) {
#pragma unroll
            for (int ii = 0; ii < 5; ++ii) {
                const int t5 = 5 * wv + ii;
                const int Rb = t5 * 16 + rg * 4;
                if (t5 < 64) {
#pragma unroll
                    for (int r = 0; r < 4; ++r)
                        gactG[(Rb + r) * 9 + c16] = (unsigned short)bf16rne(acc[ii][r]);
                } else {
#pragma unroll
                    for (int r = 0; r < 4; ++r)
                        gactF[(Rb - 1024 + r) * 9 + c16] = acc[ii][r];
                }
            }
        }
        barL();   // closes slots + publishes gact

        float g0A = 0.f, g1A = 0.f, g2A = 0.f, g3A = 0.f;
        float g0B = 0.f, g1B = 0.f, g2B = 0.f, g3B = 0.f;
        if (i < TPn) {
            g0A = bfu(gactG[u * 9 + sA]);         g0B = bfu(gactG[u * 9 + sB]);
            g1A = bfu(gactG[(256 + u) * 9 + sA]); g1B = bfu(gactG[(256 + u) * 9 + sB]);
            g2A = bfu(gactG[(512 + u) * 9 + sA]); g2B = bfu(gactG[(512 + u) * 9 + sB]);
            g3A = bfu(gactG[(768 + u) * 9 + sA]); g3B = bfu(gactG[(768 + u) * 9 + sB]);
        }
        float scA = 0.f, scB = 0.f;
        if (i > 0) {
            scA = gactF[u * 9 + sA] + fb;
            scB = gactF[u * 9 + sB] + fb;
            unsigned long long kA = amax_key(scA, u);
            unsigned long long kB = amax_key(scB, u);
#pragma unroll
            for (int off = 4; off < 64; off <<= 1) {
                unsigned long long oA = __shfl_xor(kA, off, 64);
                unsigned long long oB = __shfl_xor(kB, off, 64);
                if (oA > kA) kA = oA;
                if (oB > kB) kB = oB;
            }
            if (ln < 4) {
                atomicMax(&gmax[(i & 1) * 8 + sA], kA);
                atomicMax(&gmax[(i & 1) * 8 + sB], kB);
            }
        }
        barL();   // bar2: gmax visible; gact reads done

        int tokA = sos0, tokB = sos0;
        if (i > 0) {
            tokA = (Vn - 1) - (int)(gmax[(i & 1) * 8 + sA] & 0xffffffffu);
            tokB = (Vn - 1) - (int)(gmax[(i & 1) * 8 + sB] & 0xffffffffu);
        }
        if (i < TPn) {
            pA = Ptu[tokA * Hn + u];
            pB = Ptu[tokB * Hn + u];
        }
        if (i > 0) {
            out[((long)(wg * NSV + sA) * TPn + (i - 1)) * Vn + u] = scA;
            out[((long)(wg * NSV + sB) * TPn + (i - 1)) * Vn + u] = scB;
            if (tid < NSV) gmax[(((i + 1) & 1)) * 8 + tid] = 0ull;
        }
        if (i < TPn && ldr) { DGLL(0, 0); DGLL(1, 1); }   // next-iter chunks under the tail
        if (i < TPn) {
            float hvA, hvB;
            {
                float gi = sigf(g0A + pA.x), gf = sigf(g1A + pA.y);
                float gg = tanh_fast(g2A + pA.z), go = sigf(g3A + pA.w);
                cA = fmaf(gf, cA, gi * gg); hvA = go * tanh_fast(cA);
            }
            {
                float gi = sigf(g0B + pB.x), gf = sigf(g1B + pB.y);
                float gg = tanh_fast(g2B + pB.z), go = sigf(g3B + pB.w);
                cB = fmaf(gf, cB, gi * gg); hvB = go * tanh_fast(cB);
            }
            unsigned short* hb16 = (unsigned short*)hBf;
            const int qh = u >> 5, gh = (u >> 3) & 3, jh = u & 7;
            hb16[(qh * 64 + gh * 16 + sA) * 8 + jh] = (unsigned short)bf16rne(hvA);
            hb16[(qh * 64 + gh * 16 + sB) * 8 + jh] = (unsigned short)bf16rne(hvB);
        }
        if (i < TPn && ldr) VMW(4);   // next chunk 0 landed; chunk 1 stays in flight
        barL();                        // bar3 == publish(chunk 0, h) for next iter
    }
#undef DGLL
}

// ---------------- launch ----------------
extern "C" void kernel_launch(void* const* d_in, const int* in_sizes, int n_in,
                              void* d_out, int out_size, void* d_ws, size_t ws_size,
                              hipStream_t stream) {
    const int*   phon = (const int*)d_in[0];
    const int*   lens = (const int*)d_in[1];
    const float* emb  = (const float*)d_in[2];
    const float* eWih = (const float*)d_in[3];
    const float* eWhh = (const float*)d_in[4];
    const float* ebih = (const float*)d_in[5];
    const float* ebhh = (const float*)d_in[6];
    const float* dWih = (const float*)d_in[7];
    const float* dWhh = (const float*)d_in[8];
    const float* dbih = (const float*)d_in[9];
    const float* dbhh = (const float*)d_in[10];
    const float* fcW  = (const float*)d_in[11];
    const float* fcb  = (const float*)d_in[12];
    const int*   sos  = (const int*)d_in[13];
    float* out = (float*)d_out;

    float4* Ptu_e = (float4*)d_ws;             // 1 MB
    float4* Ptu_d = Ptu_e + 65536;             // 1 MB
    uint4*  AWq_e = (uint4*)(Ptu_d + 65536);   // 8*64*64 u4  = 512 KB
    uint4*  AWq_d = AWq_e + 32768;             // 8*80*64 u4  = 640 KB
    float*  h0d   = (float*)(AWq_d + 40960);   // 2 MB

    make_ptab<<<256, 256, 0, stream>>>(Ptu_e, emb, eWih, ebih, ebhh);
    make_ptab<<<256, 256, 0, stream>>>(Ptu_d, emb, dWih, dbih, dbhh);
    pack_awq<<<128, 256, 0, stream>>>(AWq_e, eWhh, eWhh, 64);   // enc: gates only
    pack_awq<<<160, 256, 0, stream>>>(AWq_d, dWhh, fcW, 80);    // dec: gates + fc
    enc_kernel<<<NWG, NT, 0, stream>>>((const char*)AWq_e, Ptu_e, phon, lens, h0d);
    dec_kernel<<<NWG, NT, 0, stream>>>((const char*)AWq_d, Ptu_d, fcb, h0d, sos, out);
}

// Round 11
// 947.657 us; speedup vs baseline: 1.4631x; 1.4631x over previous
//
#include <hip/hip_runtime.h>
#include <math.h>

#define Hn   256
#define En   128
#define Vn   256
#define TPn  32
#define BTn  2048
#define NSV  8              // seqs per WG
#define NWG  (BTn / NSV)    // 256 workgroups
#define NT   1024           // 16 waves
#define SROW 260            // padded LDS row stride for score stage
#define GSTR 9              // gact row stride (floats): 8 seqs + 1 pad

#define KATTR __attribute__((amdgpu_flat_work_group_size(1024, 1024), amdgpu_waves_per_eu(4, 4)))

typedef __attribute__((ext_vector_type(8))) short bf16x8;   // 8 bf16 = 4 VGPR
typedef __attribute__((ext_vector_type(4))) float f32x4;
typedef __attribute__((ext_vector_type(2))) float f32x2;    // native vec: legal for nontemporal

__device__ __forceinline__ float sigf(float x) {
    return __builtin_amdgcn_rcpf(1.0f + __expf(-x));
}
__device__ __forceinline__ float tanh_fast(float x) {
    float e = __expf(2.0f * x);
    return 1.0f - 2.0f * __builtin_amdgcn_rcpf(e + 1.0f);
}

// round-to-nearest-even f32 -> bf16 (as ushort)
__device__ __forceinline__ unsigned bf16rne(float x) {
    unsigned b = __float_as_uint(x);
    return (b + 0x7FFFu + ((b >> 16) & 1u)) >> 16;
}
__device__ __forceinline__ unsigned pk2(float a, float b) {   // elem0 -> low half
    return bf16rne(a) | (bf16rne(b) << 16);
}

__device__ __forceinline__ unsigned long long amax_key(float sc, int v) {
    unsigned fb = __float_as_uint(sc);
    fb = (fb & 0x80000000u) ? ~fb : (fb | 0x80000000u);   // order-preserving
    return ((unsigned long long)fb << 32) | (unsigned)(Vn - 1 - v);  // first-idx tie
}
__device__ __forceinline__ float dot4(float4 a, float4 b, float acc) {
    return fmaf(a.x, b.x, fmaf(a.y, b.y, fmaf(a.z, b.z, fmaf(a.w, b.w, acc))));
}

// ---------------- precompute kernels ----------------

// Ptu[v*256+u] = float4{i,f,g,o}: emb[v]@Wih[g*256+u]^T + bih + bhh   (full f32)
__global__ void make_ptab(float4* __restrict__ Pp, const float* __restrict__ emb,
                          const float* __restrict__ Wih, const float* __restrict__ bih,
                          const float* __restrict__ bhh) {
    int v = blockIdx.x, u = threadIdx.x;
    __shared__ __align__(16) float es[En];
    if (u < En) es[u] = emb[v * En + u];
    __syncthreads();
    float a[4];
#pragma unroll
    for (int g = 0; g < 4; ++g) {
        int r = g * Hn + u;
        float acc = bih[r] + bhh[r];
        const float4* w4 = (const float4*)(Wih + r * En);
        const float4* e4 = (const float4*)es;
        for (int k = 0; k < En / 4; ++k) acc = dot4(w4[k], e4[k], acc);
        a[g] = acc;
    }
    Pp[v * Hn + u] = make_float4(a[0], a[1], a[2], a[3]);
}

// A-fragment pack for mfma_f32_16x16x32_bf16.
// Wcat rows: 0..1023 = Whh (gate g*256+u), 1024..1279 = fcW (row v).
// A[idx], idx = (t*8+q)*64 + l  -> 8 bf16 of Wcat[16t + (l&15)][32q + 8*(l>>4) .. +7].
__global__ void pack_afrag(uint4* __restrict__ A, const float* __restrict__ Whh,
                           const float* __restrict__ fcW, int ntile) {
    int idx = blockIdx.x * 256 + threadIdx.x;
    if (idx >= ntile * 512) return;
    int l = idx & 63, q = (idx >> 6) & 7, t = idx >> 9;
    int r = 16 * t + (l & 15);
    int kb = 32 * q + 8 * (l >> 4);
    const float* s = (r < 1024) ? (Whh + r * Hn + kb) : (fcW + (r - 1024) * Hn + kb);
    A[idx] = make_uint4(pk2(s[0], s[1]), pk2(s[2], s[3]), pk2(s[4], s[5]), pk2(s[6], s[7]));
}

// ---------------- encoder ----------------
// Per step: G = Wcat(1024x256) x h^T(256x8) via MFMA (wave owns 4 M-tiles).
// Register diet: bf loaded per-q (no bf[8] hoist); Ptu loads issued AFTER the
// MFMA q-loop (land by bar1's vmcnt drain) -- keeps live arch-VGPRs < 64.
__global__ KATTR void enc_kernel(
    const bf16x8* __restrict__ AW, const float4* __restrict__ Ptu,
    const int* __restrict__ phon, const int* __restrict__ lens,
    float* __restrict__ h0dec) {
    const int tid = threadIdx.x, wg = blockIdx.x;
    const int wv = tid >> 6, l = tid & 63;
    const int c16 = l & 15, rg = l >> 4;
    const int u = tid >> 2, ch = tid & 3;
    const int sA = 2 * ch, sB = 2 * ch + 1;
    __shared__ __align__(16) uint4 hBf[8 * 64];      // B-fragments; cols 8..15 stay 0
    __shared__ float gact[1024 * GSTR];              // 36.9 KB
    __shared__ int lsh[NSV];

    if (tid < 512) hBf[tid] = make_uint4(0u, 0u, 0u, 0u);   // h0 = 0
    if (tid < NSV) lsh[tid] = lens[wg * NSV + tid];
    float cA = 0.f, cB = 0.f;
    __syncthreads();
    int mx = 0;
#pragma unroll
    for (int i = 0; i < NSV; ++i) mx = max(mx, lsh[i]);
    const int lenA = lsh[sA], lenB = lsh[sB];

    const bf16x8* AWw = AW + (4 * wv) * 512 + l;   // wave's first tile, this lane

    for (int t = 0; t < mx; ++t) {
        const int tokA = phon[(wg * NSV + sA) * TPn + t];
        const int tokB = phon[(wg * NSV + sB) * TPn + t];

        f32x4 acc[4];
#pragma unroll
        for (int ii = 0; ii < 4; ++ii) acc[ii] = (f32x4){0.f, 0.f, 0.f, 0.f};
#pragma unroll
        for (int q = 0; q < 8; ++q) {
            bf16x8 bf = *(const bf16x8*)&hBf[q * 64 + l];   // per-q: 4 regs live, not 32
#pragma unroll
            for (int ii = 0; ii < 4; ++ii) {
                acc[ii] = __builtin_amdgcn_mfma_f32_16x16x32_bf16(
                    AWw[ii * 512 + q * 64], bf, acc[ii], 0, 0, 0);
            }
        }
        // Ptu issued here: in flight during C-write, guaranteed landed by bar1
        const float4 pA = Ptu[tokA * Hn + u];
        const float4 pB = Ptu[tokB * Hn + u];
        if (c16 < 8) {   // C layout: col=lane&15 (seq), row=(lane>>4)*4+reg [m89-verified]
#pragma unroll
            for (int ii = 0; ii < 4; ++ii) {
                int Rb = (4 * wv + ii) * 16 + rg * 4;
#pragma unroll
                for (int r = 0; r < 4; ++r) gact[(Rb + r) * GSTR + c16] = acc[ii][r];
            }
        }
        __syncthreads();   // bar1: gact visible; hBf reads done

        float g0A = gact[(u) * GSTR + sA],       g0B = gact[(u) * GSTR + sB];
        float g1A = gact[(256 + u) * GSTR + sA], g1B = gact[(256 + u) * GSTR + sB];
        float g2A = gact[(512 + u) * GSTR + sA], g2B = gact[(512 + u) * GSTR + sB];
        float g3A = gact[(768 + u) * GSTR + sA], g3B = gact[(768 + u) * GSTR + sB];
        float hvA, hvB;
        {
            float gi = sigf(g0A + pA.x), gf = sigf(g1A + pA.y);
            float gg = tanh_fast(g2A + pA.z), go = sigf(g3A + pA.w);
            cA = fmaf(gf, cA, gi * gg); hvA = go * tanh_fast(cA);
        }
        {
            float gi = sigf(g0B + pB.x), gf = sigf(g1B + pB.y);
            float gg = tanh_fast(g2B + pB.z), go = sigf(g3B + pB.w);
            cB = fmaf(gf, cB, gi * gg); hvB = go * tanh_fast(cB);
        }
        if (t == lenA - 1) __builtin_nontemporal_store(hvA, &h0dec[(wg * NSV + sA) * Hn + u]);
        if (t == lenB - 1) __builtin_nontemporal_store(hvB, &h0dec[(wg * NSV + sB) * Hn + u]);
        {   // write new h into B-fragment layout (k=u -> q=u>>5, g=(u>>3)&3, j=u&7)
            unsigned short* hb16 = (unsigned short*)hBf;
            int q = u >> 5, g = (u >> 3) & 3, j = u & 7;
            hb16[(q * 64 + g * 16 + sA) * 8 + j] = (unsigned short)bf16rne(hvA);
            hb16[(q * 64 + g * 16 + sB) * 8 + j] = (unsigned short)bf16rne(hvB);
        }
        __syncthreads();   // bar2: new h fragments visible
    }
}

// ---------------- decoder ----------------
// M = 1280 (1024 gates + 256 fc) fused; wave owns 5 M-tiles; 3 barriers/iter.
// Same register diet: per-q bf, no long-lived prefetches.
__global__ KATTR void dec_kernel(
    const bf16x8* __restrict__ AW, const float4* __restrict__ Ptu,
    const float* __restrict__ fcb, const float* __restrict__ h0dec,
    const int* __restrict__ sosp, float* __restrict__ out) {
    const int tid = threadIdx.x, wg = blockIdx.x;
    const int wv = tid >> 6, l = tid & 63;
    const int c16 = l & 15, rg = l >> 4;
    const int u = tid >> 2, ch = tid & 3;
    const int sA = 2 * ch, sB = 2 * ch + 1;
    const int ln = tid & 63;
    __shared__ __align__(16) uint4 hBf[8 * 64];      // B-fragments; cols 8..15 stay 0
    __shared__ float gact[1280 * GSTR];              // 46.1 KB
    __shared__ float scx[NSV * SROW];
    __shared__ unsigned long long gmax[2][NSV];

    if (tid < 512) {   // stage h0 directly into B-fragment layout
        int q = tid >> 6, ll = tid & 63, c = ll & 15, g = ll >> 4;
        uint4 v = make_uint4(0u, 0u, 0u, 0u);
        if (c < 8) {
            const float* hp = h0dec + (wg * NSV + c) * Hn + 32 * q + 8 * g;
            float4 v0 = *(const float4*)hp;
            float4 v1 = *(const float4*)(hp + 4);
            v = make_uint4(pk2(v0.x, v0.y), pk2(v0.z, v0.w), pk2(v1.x, v1.y), pk2(v1.z, v1.w));
        }
        hBf[tid] = v;
    }
    if (tid < 2 * NSV) ((unsigned long long*)gmax)[tid] = 0ull;
    const int sos0 = sosp[0];
    const float fb = fcb[u];
    float cA = 0.f, cB = 0.f;
    __syncthreads();

    const bf16x8* AWw = AW + (5 * wv) * 512 + l;   // wave's first tile, this lane

    for (int i = 0; i <= TPn; ++i) {
        const bool full = (i < TPn);

        f32x4 acc[5];
#pragma unroll
        for (int ii = 0; ii < 5; ++ii) acc[ii] = (f32x4){0.f, 0.f, 0.f, 0.f};
#pragma unroll
        for (int q = 0; q < 8; ++q) {
            bf16x8 bf = *(const bf16x8*)&hBf[q * 64 + l];   // per-q
#pragma unroll
            for (int ii = 0; ii < 5; ++ii) {
                acc[ii] = __builtin_amdgcn_mfma_f32_16x16x32_bf16(
                    AWw[ii * 512 + q * 64], bf, acc[ii], 0, 0, 0);
            }
        }
        if (c16 < 8) {
#pragma unroll
            for (int ii = 0; ii < 5; ++ii) {
                int Rb = (5 * wv + ii) * 16 + rg * 4;
#pragma unroll
                for (int r = 0; r < 4; ++r) gact[(Rb + r) * GSTR + c16] = acc[ii][r];
            }
        }
        __syncthreads();   // bar1: gact visible; hBf reads done

        float g0A = 0.f, g1A = 0.f, g2A = 0.f, g3A = 0.f;
        float g0B = 0.f, g1B = 0.f, g2B = 0.f, g3B = 0.f;
        if (full) {
            g0A = gact[(u) * GSTR + sA];       g0B = gact[(u) * GSTR + sB];
            g1A = gact[(256 + u) * GSTR + sA]; g1B = gact[(256 + u) * GSTR + sB];
            g2A = gact[(512 + u) * GSTR + sA]; g2B = gact[(512 + u) * GSTR + sB];
            g3A = gact[(768 + u) * GSTR + sA]; g3B = gact[(768 + u) * GSTR + sB];
        }
        if (i > 0) {   // scores_{i-1} for v=u, seqs sA,sB (fc rows 1024+v)
            float scA = gact[(1024 + u) * GSTR + sA] + fb;
            float scB = gact[(1024 + u) * GSTR + sB] + fb;
            scx[sA * SROW + u] = scA;
            scx[sB * SROW + u] = scB;
            unsigned long long kA = amax_key(scA, u);
            unsigned long long kB = amax_key(scB, u);
#pragma unroll
            for (int off = 4; off < 64; off <<= 1) {
                unsigned long long oA = __shfl_xor(kA, off, 64);
                unsigned long long oB = __shfl_xor(kB, off, 64);
                if (oA > kA) kA = oA;
                if (oB > kB) kB = oB;
            }
            if (ln < 4) {
                atomicMax(&gmax[i & 1][sA], kA);
                atomicMax(&gmax[i & 1][sB], kB);
            }
        }
        __syncthreads();   // bar2: scx + gmax visible; gact reads done

        int tokA = sos0, tokB = sos0;
        if (i > 0) {
            {   // coalesced nt store of scores_{i-1}
                int s = tid >> 7, k = (tid & 127) * 2;
                f32x2 v = *(const f32x2*)&scx[s * SROW + k];
                __builtin_nontemporal_store(
                    v, (f32x2*)&out[((long)(wg * NSV + s) * TPn + (i - 1)) * Vn + k]);
            }
            tokA = (Vn - 1) - (int)(gmax[i & 1][sA] & 0xffffffffu);
            tokB = (Vn - 1) - (int)(gmax[i & 1][sB] & 0xffffffffu);
            if (tid < NSV) gmax[(i + 1) & 1][tid] = 0ull;   // reset other parity slot
        }

        if (full) {
            const float4 pA = Ptu[tokA * Hn + u];
            const float4 pB = Ptu[tokB * Hn + u];
            float hvA, hvB;
            {
                float gi = sigf(g0A + pA.x), gf = sigf(g1A + pA.y);
                float gg = tanh_fast(g2A + pA.z), go = sigf(g3A + pA.w);
                cA = fmaf(gf, cA, gi * gg); hvA = go * tanh_fast(cA);
            }
            {
                float gi = sigf(g0B + pB.x), gf = sigf(g1B + pB.y);
                float gg = tanh_fast(g2B + pB.z), go = sigf(g3B + pB.w);
                cB = fmaf(gf, cB, gi * gg); hvB = go * tanh_fast(cB);
            }
            unsigned short* hb16 = (unsigned short*)hBf;
            int q = u >> 5, g = (u >> 3) & 3, j = u & 7;
            hb16[(q * 64 + g * 16 + sA) * 8 + j] = (unsigned short)bf16rne(hvA);
            hb16[(q * 64 + g * 16 + sB) * 8 + j] = (unsigned short)bf16rne(hvB);
        }
        __syncthreads();   // bar3: new h fragments + gmax reset visible
    }
}

// ---------------- launch ----------------
extern "C" void kernel_launch(void* const* d_in, const int* in_sizes, int n_in,
                              void* d_out, int out_size, void* d_ws, size_t ws_size,
                              hipStream_t stream) {
    const int*   phon = (const int*)d_in[0];
    const int*   lens = (const int*)d_in[1];
    const float* emb  = (const float*)d_in[2];
    const float* eWih = (const float*)d_in[3];
    const float* eWhh = (const float*)d_in[4];
    const float* ebih = (const float*)d_in[5];
    const float* ebhh = (const float*)d_in[6];
    const float* dWih = (const float*)d_in[7];
    const float* dWhh = (const float*)d_in[8];
    const float* dbih = (const float*)d_in[9];
    const float* dbhh = (const float*)d_in[10];
    const float* fcW  = (const float*)d_in[11];
    const float* fcb  = (const float*)d_in[12];
    const int*   sos  = (const int*)d_in[13];
    float* out = (float*)d_out;

    float4* Ptu_e = (float4*)d_ws;            // 65536 f4 = 1 MB
    float4* Ptu_d = Ptu_e + 65536;            // 1 MB
    uint4*  AW_e  = (uint4*)(Ptu_d + 65536);  // 64 tiles * 512 = 32768 u4 = 512 KB
    uint4*  AW_d  = AW_e + 32768;             // 80 tiles * 512 = 40960 u4 = 640 KB
    float*  h0d   = (float*)(AW_d + 40960);   // 2 MB

    make_ptab<<<256, 256, 0, stream>>>(Ptu_e, emb, eWih, ebih, ebhh);
    make_ptab<<<256, 256, 0, stream>>>(Ptu_d, emb, dWih, dbih, dbhh);
    pack_afrag<<<128, 256, 0, stream>>>(AW_e, eWhh, eWhh, 64);   // fcW unused (ntile=64)
    pack_afrag<<<160, 256, 0, stream>>>(AW_d, dWhh, fcW, 80);
    enc_kernel<<<NWG, NT, 0, stream>>>((const bf16x8*)AW_e, Ptu_e, phon, lens, h0d);
    dec_kernel<<<NWG, NT, 0, stream>>>((const bf16x8*)AW_d, Ptu_d, fcb, h0d, sos, out);
}

// Round 12
// 741.842 us; speedup vs baseline: 1.8690x; 1.2774x over previous
//
#include <hip/hip_runtime.h>
#include <math.h>

#define Hn   256
#define En   128
#define Vn   256
#define TPn  32
#define BTn  2048
#define NSV  8              // seqs per WG
#define NWG  (BTn / NSV)    // 256 workgroups
#define NT   1024           // 16 waves
#define SROW 260            // padded LDS row stride for score stage
#define GSTR 9              // gact row stride (floats): 8 seqs + 1 pad
#define RESQ_E 7            // enc: resident q-chunks of each wave's tile 0 (of 8)
#define RESQ_D 6            // dec: resident q-chunks of each wave's tile 0 (of 8)

#define KATTR __attribute__((amdgpu_flat_work_group_size(1024, 1024), amdgpu_waves_per_eu(4, 4)))

typedef __attribute__((ext_vector_type(8))) short bf16x8;   // 8 bf16 = 4 VGPR
typedef __attribute__((ext_vector_type(4))) float f32x4;
typedef __attribute__((ext_vector_type(2))) float f32x2;    // native vec: legal for nontemporal

__device__ __forceinline__ float sigf(float x) {
    return __builtin_amdgcn_rcpf(1.0f + __expf(-x));
}
__device__ __forceinline__ float tanh_fast(float x) {
    float e = __expf(2.0f * x);
    return 1.0f - 2.0f * __builtin_amdgcn_rcpf(e + 1.0f);
}

// round-to-nearest-even f32 -> bf16 (as ushort)
__device__ __forceinline__ unsigned bf16rne(float x) {
    unsigned b = __float_as_uint(x);
    return (b + 0x7FFFu + ((b >> 16) & 1u)) >> 16;
}
__device__ __forceinline__ unsigned pk2(float a, float b) {   // elem0 -> low half
    return bf16rne(a) | (bf16rne(b) << 16);
}

__device__ __forceinline__ unsigned long long amax_key(float sc, int v) {
    unsigned fb = __float_as_uint(sc);
    fb = (fb & 0x80000000u) ? ~fb : (fb | 0x80000000u);   // order-preserving
    return ((unsigned long long)fb << 32) | (unsigned)(Vn - 1 - v);  // first-idx tie
}
__device__ __forceinline__ float dot4(float4 a, float4 b, float acc) {
    return fmaf(a.x, b.x, fmaf(a.y, b.y, fmaf(a.z, b.z, fmaf(a.w, b.w, acc))));
}

// ---------------- precompute kernels ----------------

// Ptu[v*256+u] = float4{i,f,g,o}: emb[v]@Wih[g*256+u]^T + bih + bhh   (full f32)
__global__ void make_ptab(float4* __restrict__ Pp, const float* __restrict__ emb,
                          const float* __restrict__ Wih, const float* __restrict__ bih,
                          const float* __restrict__ bhh) {
    int v = blockIdx.x, u = threadIdx.x;
    __shared__ __align__(16) float es[En];
    if (u < En) es[u] = emb[v * En + u];
    __syncthreads();
    float a[4];
#pragma unroll
    for (int g = 0; g < 4; ++g) {
        int r = g * Hn + u;
        float acc = bih[r] + bhh[r];
        const float4* w4 = (const float4*)(Wih + r * En);
        const float4* e4 = (const float4*)es;
        for (int k = 0; k < En / 4; ++k) acc = dot4(w4[k], e4[k], acc);
        a[g] = acc;
    }
    Pp[v * Hn + u] = make_float4(a[0], a[1], a[2], a[3]);
}

// A-fragment pack for mfma_f32_16x16x32_bf16.
// Wcat rows: 0..1023 = Whh (gate g*256+u), 1024..1279 = fcW (row v).
// A[idx], idx = (t*8+q)*64 + l  -> 8 bf16 of Wcat[16t + (l&15)][32q + 8*(l>>4) .. +7].
__global__ void pack_afrag(uint4* __restrict__ A, const float* __restrict__ Whh,
                           const float* __restrict__ fcW, int ntile) {
    int idx = blockIdx.x * 256 + threadIdx.x;
    if (idx >= ntile * 512) return;
    int l = idx & 63, q = (idx >> 6) & 7, t = idx >> 9;
    int r = 16 * t + (l & 15);
    int kb = 32 * q + 8 * (l >> 4);
    const float* s = (r < 1024) ? (Whh + r * Hn + kb) : (fcW + (r - 1024) * Hn + kb);
    A[idx] = make_uint4(pk2(s[0], s[1]), pk2(s[2], s[3]), pk2(s[4], s[5]), pk2(s[6], s[7]));
}

// ---------------- encoder ----------------
// Per step: G = Wcat(1024x256) x h^T(256x8) via MFMA (wave owns 4 M-tiles).
// NEW: each wave pins q=0..6 of its tile 0 in LDS (wave-private, loaded once in
// the prologue) -- moves 22% of the per-iter weight stream off the global path.
__global__ KATTR void enc_kernel(
    const bf16x8* __restrict__ AW, const float4* __restrict__ Ptu,
    const int* __restrict__ phon, const int* __restrict__ lens,
    float* __restrict__ h0dec) {
    const int tid = threadIdx.x, wg = blockIdx.x;
    const int wv = tid >> 6, l = tid & 63;
    const int c16 = l & 15, rg = l >> 4;
    const int u = tid >> 2, ch = tid & 3;
    const int sA = 2 * ch, sB = 2 * ch + 1;
    __shared__ __align__(16) bf16x8 resW[16 * RESQ_E * 64];   // 114,688 B
    __shared__ __align__(16) uint4 hBf[8 * 64];               // B-frags; cols 8..15 = 0
    __shared__ float gact[1024 * GSTR];                       // 36,864 B
    __shared__ int lsh[NSV];

    if (tid < 512) hBf[tid] = make_uint4(0u, 0u, 0u, 0u);   // h0 = 0
    if (tid < NSV) lsh[tid] = lens[wg * NSV + tid];
#pragma unroll
    for (int q = 0; q < RESQ_E; ++q)   // wave-private resident copy of tile0 q<7
        resW[(wv * RESQ_E + q) * 64 + l] = AW[((4 * wv) * 8 + q) * 64 + l];
    float cA = 0.f, cB = 0.f;
    __syncthreads();
    int mx = 0;
#pragma unroll
    for (int i = 0; i < NSV; ++i) mx = max(mx, lsh[i]);
    const int lenA = lsh[sA], lenB = lsh[sB];

    const bf16x8* AWw = AW + (4 * wv) * 512 + l;   // wave's first tile, this lane

    for (int t = 0; t < mx; ++t) {
        const int tokA = phon[(wg * NSV + sA) * TPn + t];
        const int tokB = phon[(wg * NSV + sB) * TPn + t];

        f32x4 acc[4];
#pragma unroll
        for (int ii = 0; ii < 4; ++ii) acc[ii] = (f32x4){0.f, 0.f, 0.f, 0.f};
#pragma unroll
        for (int q = 0; q < 8; ++q) {
            bf16x8 bf = *(const bf16x8*)&hBf[q * 64 + l];
            // ii == 0: resident in LDS for q < RESQ_E
            bf16x8 a0 = (q < RESQ_E) ? resW[(wv * RESQ_E + q) * 64 + l]
                                     : AWw[q * 64];
            acc[0] = __builtin_amdgcn_mfma_f32_16x16x32_bf16(a0, bf, acc[0], 0, 0, 0);
#pragma unroll
            for (int ii = 1; ii < 4; ++ii) {
                acc[ii] = __builtin_amdgcn_mfma_f32_16x16x32_bf16(
                    AWw[ii * 512 + q * 64], bf, acc[ii], 0, 0, 0);
            }
        }
        // Ptu issued here: in flight during C-write, landed by bar1
        const float4 pA = Ptu[tokA * Hn + u];
        const float4 pB = Ptu[tokB * Hn + u];
        if (c16 < 8) {   // C layout: col=lane&15 (seq), row=(lane>>4)*4+reg [m89-verified]
#pragma unroll
            for (int ii = 0; ii < 4; ++ii) {
                int Rb = (4 * wv + ii) * 16 + rg * 4;
#pragma unroll
                for (int r = 0; r < 4; ++r) gact[(Rb + r) * GSTR + c16] = acc[ii][r];
            }
        }
        __syncthreads();   // bar1: gact visible; hBf reads done

        float g0A = gact[(u) * GSTR + sA],       g0B = gact[(u) * GSTR + sB];
        float g1A = gact[(256 + u) * GSTR + sA], g1B = gact[(256 + u) * GSTR + sB];
        float g2A = gact[(512 + u) * GSTR + sA], g2B = gact[(512 + u) * GSTR + sB];
        float g3A = gact[(768 + u) * GSTR + sA], g3B = gact[(768 + u) * GSTR + sB];
        float hvA, hvB;
        {
            float gi = sigf(g0A + pA.x), gf = sigf(g1A + pA.y);
            float gg = tanh_fast(g2A + pA.z), go = sigf(g3A + pA.w);
            cA = fmaf(gf, cA, gi * gg); hvA = go * tanh_fast(cA);
        }
        {
            float gi = sigf(g0B + pB.x), gf = sigf(g1B + pB.y);
            float gg = tanh_fast(g2B + pB.z), go = sigf(g3B + pB.w);
            cB = fmaf(gf, cB, gi * gg); hvB = go * tanh_fast(cB);
        }
        if (t == lenA - 1) __builtin_nontemporal_store(hvA, &h0dec[(wg * NSV + sA) * Hn + u]);
        if (t == lenB - 1) __builtin_nontemporal_store(hvB, &h0dec[(wg * NSV + sB) * Hn + u]);
        {   // write new h into B-fragment layout (k=u -> q=u>>5, g=(u>>3)&3, j=u&7)
            unsigned short* hb16 = (unsigned short*)hBf;
            int q = u >> 5, g = (u >> 3) & 3, j = u & 7;
            hb16[(q * 64 + g * 16 + sA) * 8 + j] = (unsigned short)bf16rne(hvA);
            hb16[(q * 64 + g * 16 + sB) * 8 + j] = (unsigned short)bf16rne(hvB);
        }
        __syncthreads();   // bar2: new h fragments visible
    }
}

// ---------------- decoder ----------------
// M = 1280 (1024 gates + 256 fc) fused; wave owns 5 M-tiles; 3 barriers/iter.
// NEW: q=0..5 of each wave's tile 0 resident in LDS (96 KB) -- -15% global stream.
__global__ KATTR void dec_kernel(
    const bf16x8* __restrict__ AW, const float4* __restrict__ Ptu,
    const float* __restrict__ fcb, const float* __restrict__ h0dec,
    const int* __restrict__ sosp, float* __restrict__ out) {
    const int tid = threadIdx.x, wg = blockIdx.x;
    const int wv = tid >> 6, l = tid & 63;
    const int c16 = l & 15, rg = l >> 4;
    const int u = tid >> 2, ch = tid & 3;
    const int sA = 2 * ch, sB = 2 * ch + 1;
    const int ln = tid & 63;
    __shared__ __align__(16) bf16x8 resW[16 * RESQ_D * 64];   // 98,304 B
    __shared__ __align__(16) uint4 hBf[8 * 64];               // 8,192 B
    __shared__ float gact[1280 * GSTR];                       // 46,080 B
    __shared__ float scx[NSV * SROW];                         // 8,320 B
    __shared__ unsigned long long gmax[2][NSV];               // 128 B -> 161,024 total

    if (tid < 512) {   // stage h0 directly into B-fragment layout
        int q = tid >> 6, ll = tid & 63, c = ll & 15, g = ll >> 4;
        uint4 v = make_uint4(0u, 0u, 0u, 0u);
        if (c < 8) {
            const float* hp = h0dec + (wg * NSV + c) * Hn + 32 * q + 8 * g;
            float4 v0 = *(const float4*)hp;
            float4 v1 = *(const float4*)(hp + 4);
            v = make_uint4(pk2(v0.x, v0.y), pk2(v0.z, v0.w), pk2(v1.x, v1.y), pk2(v1.z, v1.w));
        }
        hBf[tid] = v;
    }
    if (tid < 2 * NSV) ((unsigned long long*)gmax)[tid] = 0ull;
#pragma unroll
    for (int q = 0; q < RESQ_D; ++q)   // wave-private resident copy of tile0 q<6
        resW[(wv * RESQ_D + q) * 64 + l] = AW[((5 * wv) * 8 + q) * 64 + l];
    const int sos0 = sosp[0];
    const float fb = fcb[u];
    float cA = 0.f, cB = 0.f;
    __syncthreads();

    const bf16x8* AWw = AW + (5 * wv) * 512 + l;   // wave's first tile, this lane

    for (int i = 0; i <= TPn; ++i) {
        const bool full = (i < TPn);

        f32x4 acc[5];
#pragma unroll
        for (int ii = 0; ii < 5; ++ii) acc[ii] = (f32x4){0.f, 0.f, 0.f, 0.f};
#pragma unroll
        for (int q = 0; q < 8; ++q) {
            bf16x8 bf = *(const bf16x8*)&hBf[q * 64 + l];
            bf16x8 a0 = (q < RESQ_D) ? resW[(wv * RESQ_D + q) * 64 + l]
                                     : AWw[q * 64];
            acc[0] = __builtin_amdgcn_mfma_f32_16x16x32_bf16(a0, bf, acc[0], 0, 0, 0);
#pragma unroll
            for (int ii = 1; ii < 5; ++ii) {
                acc[ii] = __builtin_amdgcn_mfma_f32_16x16x32_bf16(
                    AWw[ii * 512 + q * 64], bf, acc[ii], 0, 0, 0);
            }
        }
        if (c16 < 8) {
#pragma unroll
            for (int ii = 0; ii < 5; ++ii) {
                int Rb = (5 * wv + ii) * 16 + rg * 4;
#pragma unroll
                for (int r = 0; r < 4; ++r) gact[(Rb + r) * GSTR + c16] = acc[ii][r];
            }
        }
        __syncthreads();   // bar1: gact visible; hBf reads done

        float g0A = 0.f, g1A = 0.f, g2A = 0.f, g3A = 0.f;
        float g0B = 0.f, g1B = 0.f, g2B = 0.f, g3B = 0.f;
        if (full) {
            g0A = gact[(u) * GSTR + sA];       g0B = gact[(u) * GSTR + sB];
            g1A = gact[(256 + u) * GSTR + sA]; g1B = gact[(256 + u) * GSTR + sB];
            g2A = gact[(512 + u) * GSTR + sA]; g2B = gact[(512 + u) * GSTR + sB];
            g3A = gact[(768 + u) * GSTR + sA]; g3B = gact[(768 + u) * GSTR + sB];
        }
        if (i > 0) {   // scores_{i-1} for v=u, seqs sA,sB (fc rows 1024+v)
            float scA = gact[(1024 + u) * GSTR + sA] + fb;
            float scB = gact[(1024 + u) * GSTR + sB] + fb;
            scx[sA * SROW + u] = scA;
            scx[sB * SROW + u] = scB;
            unsigned long long kA = amax_key(scA, u);
            unsigned long long kB = amax_key(scB, u);
#pragma unroll
            for (int off = 4; off < 64; off <<= 1) {
                unsigned long long oA = __shfl_xor(kA, off, 64);
                unsigned long long oB = __shfl_xor(kB, off, 64);
                if (oA > kA) kA = oA;
                if (oB > kB) kB = oB;
            }
            if (ln < 4) {
                atomicMax(&gmax[i & 1][sA], kA);
                atomicMax(&gmax[i & 1][sB], kB);
            }
        }
        __syncthreads();   // bar2: scx + gmax visible; gact reads done

        int tokA = sos0, tokB = sos0;
        if (i > 0) {
            {   // coalesced nt store of scores_{i-1}
                int s = tid >> 7, k = (tid & 127) * 2;
                f32x2 v = *(const f32x2*)&scx[s * SROW + k];
                __builtin_nontemporal_store(
                    v, (f32x2*)&out[((long)(wg * NSV + s) * TPn + (i - 1)) * Vn + k]);
            }
            tokA = (Vn - 1) - (int)(gmax[i & 1][sA] & 0xffffffffu);
            tokB = (Vn - 1) - (int)(gmax[i & 1][sB] & 0xffffffffu);
            if (tid < NSV) gmax[(i + 1) & 1][tid] = 0ull;   // reset other parity slot
        }

        if (full) {
            const float4 pA = Ptu[tokA * Hn + u];
            const float4 pB = Ptu[tokB * Hn + u];
            float hvA, hvB;
            {
                float gi = sigf(g0A + pA.x), gf = sigf(g1A + pA.y);
                float gg = tanh_fast(g2A + pA.z), go = sigf(g3A + pA.w);
                cA = fmaf(gf, cA, gi * gg); hvA = go * tanh_fast(cA);
            }
            {
                float gi = sigf(g0B + pB.x), gf = sigf(g1B + pB.y);
                float gg = tanh_fast(g2B + pB.z), go = sigf(g3B + pB.w);
                cB = fmaf(gf, cB, gi * gg); hvB = go * tanh_fast(cB);
            }
            unsigned short* hb16 = (unsigned short*)hBf;
            int q = u >> 5, g = (u >> 3) & 3, j = u & 7;
            hb16[(q * 64 + g * 16 + sA) * 8 + j] = (unsigned short)bf16rne(hvA);
            hb16[(q * 64 + g * 16 + sB) * 8 + j] = (unsigned short)bf16rne(hvB);
        }
        __syncthreads();   // bar3: new h fragments + gmax reset visible
    }
}

// ---------------- launch ----------------
extern "C" void kernel_launch(void* const* d_in, const int* in_sizes, int n_in,
                              void* d_out, int out_size, void* d_ws, size_t ws_size,
                              hipStream_t stream) {
    const int*   phon = (const int*)d_in[0];
    const int*   lens = (const int*)d_in[1];
    const float* emb  = (const float*)d_in[2];
    const float* eWih = (const float*)d_in[3];
    const float* eWhh = (const float*)d_in[4];
    const float* ebih = (const float*)d_in[5];
    const float* ebhh = (const float*)d_in[6];
    const float* dWih = (const float*)d_in[7];
    const float* dWhh = (const float*)d_in[8];
    const float* dbih = (const float*)d_in[9];
    const float* dbhh = (const float*)d_in[10];
    const float* fcW  = (const float*)d_in[11];
    const float* fcb  = (const float*)d_in[12];
    const int*   sos  = (const int*)d_in[13];
    float* out = (float*)d_out;

    float4* Ptu_e = (float4*)d_ws;            // 65536 f4 = 1 MB
    float4* Ptu_d = Ptu_e + 65536;            // 1 MB
    uint4*  AW_e  = (uint4*)(Ptu_d + 65536);  // 64 tiles * 512 = 32768 u4 = 512 KB
    uint4*  AW_d  = AW_e + 32768;             // 80 tiles * 512 = 40960 u4 = 640 KB
    float*  h0d   = (float*)(AW_d + 40960);   // 2 MB

    make_ptab<<<256, 256, 0, stream>>>(Ptu_e, emb, eWih, ebih, ebhh);
    make_ptab<<<256, 256, 0, stream>>>(Ptu_d, emb, dWih, dbih, dbhh);
    pack_afrag<<<128, 256, 0, stream>>>(AW_e, eWhh, eWhh, 64);   // fcW unused (ntile=64)
    pack_afrag<<<160, 256, 0, stream>>>(AW_d, dWhh, fcW, 80);
    enc_kernel<<<NWG, NT, 0, stream>>>((const bf16x8*)AW_e, Ptu_e, phon, lens, h0d);
    dec_kernel<<<NWG, NT, 0, stream>>>((const bf16x8*)AW_d, Ptu_d, fcb, h0d, sos, out);
}